// Round 7
// baseline (210.444 us; speedup 1.0000x reference)
//
#include <hip/hip_runtime.h>

// 5-layer MLP [B,64]->32->12->8->6->2, fp32. Wave-autonomous pipeline:
// each wave processes NT=4 tiles of 64 rows; x staged in 4KB column-chunks
// (64 rows x 64B) via global_load_lds, double-buffered, issue-ahead-1 with
// counted s_waitcnt vmcnt(4). Packed fp32 math forced via inline-asm
// v_pk_fma_f32 with the weight operand in an SGPR pair ("s" constraint,
// uniform s_load -> zero VALU cost for weights). XOR-swizzled LDS layout
// (slot S of super-row R holds chunk S^(R&7)) keeps ds_read_b128 conflict-
// free with a fully-coalesced pre-swizzled global source. No __syncthreads.

typedef float v2f __attribute__((ext_vector_type(2)));
typedef __attribute__((address_space(3))) void* as3p;
typedef const __attribute__((address_space(1))) void* as1p;

#define BLOCK 128   // 2 waves/block
#define NT 4        // 64-row tiles per wave

// acc = w * x + acc, packed 2xfp32. Weight comes from the scalar RF.
__device__ __forceinline__ void pk_fma(v2f& acc, v2f w, v2f x) {
    asm("v_pk_fma_f32 %0, %1, %2, %0" : "+v"(acc) : "s"(w), "v"(x));
}

template <int IN, int OUT, bool RELU>
__device__ __forceinline__ void vlayer(const float* __restrict__ W,
                                       const float* __restrict__ b,
                                       const v2f* hin, v2f* hout) {
#pragma unroll
    for (int o = 0; o < OUT / 2; ++o)
        hout[o] = *reinterpret_cast<const v2f*>(&b[2 * o]);
#pragma unroll
    for (int i = 0; i < IN; ++i) {
        const float v = hin[i >> 1][i & 1];
        const v2f xv = {v, v};
#pragma unroll
        for (int o = 0; o < OUT / 2; ++o) {
            const v2f w = *reinterpret_cast<const v2f*>(&W[i * OUT + 2 * o]);
            pk_fma(hout[o], w, xv);
        }
    }
    if (RELU) {
#pragma unroll
        for (int o = 0; o < OUT / 2; ++o) {
            hout[o][0] = fmaxf(hout[o][0], 0.0f);
            hout[o][1] = fmaxf(hout[o][1], 0.0f);
        }
    }
}

__global__ __launch_bounds__(BLOCK) void mlp_kernel(
        const float* __restrict__ x,
        const float* __restrict__ W0, const float* __restrict__ b0,
        const float* __restrict__ W1, const float* __restrict__ b1,
        const float* __restrict__ W2, const float* __restrict__ b2,
        const float* __restrict__ W3, const float* __restrict__ b3,
        const float* __restrict__ W4, const float* __restrict__ b4,
        float* __restrict__ out, int nrows) {
    extern __shared__ char lds[];
    const int t = threadIdx.x;
    const int wv = t >> 6;
    const int lane = t & 63;
    char* buf0 = lds + wv * 8192;
    char* buf1 = buf0 + 4096;

    const long long row0 = ((long long)blockIdx.x * 2 + wv) * (NT * 64);
    const char* xbase = reinterpret_cast<const char*>(x + row0 * 64);

    // per-lane constant source offset for staging (inverse of read swizzle)
    const int h = lane >> 3;
    const int q = (lane & 7) ^ h;
    const int stage_off = (2 * h + (q >> 2)) * 256 + (q & 3) * 16;

    // per-lane constant LDS read offsets (row r = lane)
    const int R = lane >> 1;
    const int p2 = lane & 1;
    const int r7 = R & 7;
    int roff[4];
#pragma unroll
    for (int j = 0; j < 4; ++j)
        roff[j] = R * 128 + (((j + 4 * p2) ^ r7) << 4);

    // prologue: stage chunk 0 into buf0
#pragma unroll
    for (int k = 0; k < 4; ++k)
        __builtin_amdgcn_global_load_lds((as1p)(xbase + k * 4096 + stage_off),
                                         (as3p)(buf0 + k * 1024), 16, 0, 0);

#pragma unroll 1
    for (int tt = 0; tt < NT; ++tt) {
        v2f acc[16];
#pragma unroll
        for (int o = 0; o < 16; ++o)
            acc[o] = *reinterpret_cast<const v2f*>(&b0[2 * o]);

#pragma unroll
        for (int c = 0; c < 4; ++c) {
            const int L = 4 * tt + c;
            char* cur = (c & 1) ? buf1 : buf0;
            char* oth = (c & 1) ? buf0 : buf1;

            // Issue chunk L+1 into the buffer consumed LAST phase (its data
            // was lgkm-waited before use, so the DMA overwrite is race-free),
            // then wait only for the current chunk (4 loads stay in flight).
            if (L + 1 < 4 * NT) {
                const int Lp = L + 1;
                const char* src =
                    xbase + (Lp >> 2) * 16384 + (Lp & 3) * 64 + stage_off;
#pragma unroll
                for (int k = 0; k < 4; ++k)
                    __builtin_amdgcn_global_load_lds((as1p)(src + k * 4096),
                                                     (as3p)(oth + k * 1024),
                                                     16, 0, 0);
                asm volatile("s_waitcnt vmcnt(4)" ::: "memory");
            } else {
                asm volatile("s_waitcnt vmcnt(0)" ::: "memory");
            }

            // conflict-free swizzled reads: 4x ds_read_b128
            float xr[16];
#pragma unroll
            for (int j = 0; j < 4; ++j) {
                const float4 v = *reinterpret_cast<const float4*>(cur + roff[j]);
                xr[4 * j + 0] = v.x; xr[4 * j + 1] = v.y;
                xr[4 * j + 2] = v.z; xr[4 * j + 3] = v.w;
            }

            // layer-0 partial: 16 i-values x 32 outputs, packed fp32
#pragma unroll
            for (int idx = 0; idx < 16; ++idx) {
                const float xval = xr[idx];
                const v2f xv = {xval, xval};
#pragma unroll
                for (int o = 0; o < 16; ++o) {
                    const v2f w = *reinterpret_cast<const v2f*>(
                        &W0[(16 * c + idx) * 32 + 2 * o]);
                    pk_fma(acc[o], w, xv);
                }
            }
        }

        // ReLU on h0
#pragma unroll
        for (int o = 0; o < 16; ++o) {
            acc[o][0] = fmaxf(acc[o][0], 0.0f);
            acc[o][1] = fmaxf(acc[o][1], 0.0f);
        }

        // tail layers (next tile's chunk 0 DMA flies during these)
        v2f h1[6], h2[4], h3[3], h4[1];
        vlayer<32, 12, true>(W1, b1, acc, h1);
        vlayer<12, 8, true>(W2, b2, h1, h2);
        vlayer<8, 6, true>(W3, b3, h2, h3);
        vlayer<6, 2, false>(W4, b4, h3, h4);

        reinterpret_cast<float2*>(out)[row0 + tt * 64 + lane] =
            make_float2(h4[0][0], h4[0][1]);
    }
}

extern "C" void kernel_launch(void* const* d_in, const int* in_sizes, int n_in,
                              void* d_out, int out_size, void* d_ws, size_t ws_size,
                              hipStream_t stream) {
    const float* x  = (const float*)d_in[0];
    const float* W0 = (const float*)d_in[1];
    const float* b0 = (const float*)d_in[2];
    const float* W1 = (const float*)d_in[3];
    const float* b1 = (const float*)d_in[4];
    const float* W2 = (const float*)d_in[5];
    const float* b2 = (const float*)d_in[6];
    const float* W3 = (const float*)d_in[7];
    const float* b3 = (const float*)d_in[8];
    const float* W4 = (const float*)d_in[9];
    const float* b4 = (const float*)d_in[10];
    float* out = (float*)d_out;

    const int nrows = in_sizes[0] / 64;                 // 1,048,576
    const int rows_per_block = 2 * NT * 64;             // 512
    const int grid = nrows / rows_per_block;             // 2048 (exact)
    const size_t shmem = 2 * 8192;                       // 16 KiB/block

    mlp_kernel<<<grid, BLOCK, shmem, stream>>>(x, W0, b0, W1, b1, W2, b2,
                                               W3, b3, W4, b4, out, nrows);
}

// Round 8
// 113.940 us; speedup vs baseline: 1.8470x; 1.8470x over previous
//
#include <hip/hip_runtime.h>

// 5-layer MLP [B,64]->32->12->8->6->2, fp32.
// Wave-autonomous DMA pipeline (R6-proven staging/swizzle, reused verbatim),
// plain fmaf weights (R1-proven: compiler s_loads them -> scalar pipe),
// 2 rows per lane (each s_loaded weight feeds 2 FMAs), NT=2 tiles per wave.
// Tile = 128 rows; chunk = 16 cols (64B) of all 128 rows = 8KB = two 4KB
// sub-chunks, each staged exactly like R6 (XOR-swizzled global source,
// linear LDS dest, conflict-free ds_read_b128). Double-buffered, counted
// s_waitcnt vmcnt(8), no __syncthreads (LDS is wave-private).

typedef __attribute__((address_space(3))) void* as3p;
typedef const __attribute__((address_space(1))) void* as1p;

#define BLOCK 128        // 2 waves/block
#define NT 2             // 128-row tiles per wave
#define TILE_ROWS 128
#define TOTAL_CHUNKS (NT * 4)

template <int IN, int OUT, bool RELU>
__device__ __forceinline__ void layer2(const float* __restrict__ W,
                                       const float* __restrict__ b,
                                       const float* in0, const float* in1,
                                       float* out0, float* out1) {
#pragma unroll
    for (int o = 0; o < OUT; ++o) { out0[o] = b[o]; out1[o] = b[o]; }
#pragma unroll
    for (int i = 0; i < IN; ++i) {
        const float v0 = in0[i];
        const float v1 = in1[i];
#pragma unroll
        for (int o = 0; o < OUT; ++o) {
            const float w = W[i * OUT + o];     // uniform -> s_load
            out0[o] = fmaf(v0, w, out0[o]);
            out1[o] = fmaf(v1, w, out1[o]);
        }
    }
    if (RELU) {
#pragma unroll
        for (int o = 0; o < OUT; ++o) {
            out0[o] = fmaxf(out0[o], 0.0f);
            out1[o] = fmaxf(out1[o], 0.0f);
        }
    }
}

__global__ __launch_bounds__(BLOCK) void mlp_kernel(
        const float* __restrict__ x,
        const float* __restrict__ W0, const float* __restrict__ b0,
        const float* __restrict__ W1, const float* __restrict__ b1,
        const float* __restrict__ W2, const float* __restrict__ b2,
        const float* __restrict__ W3, const float* __restrict__ b3,
        const float* __restrict__ W4, const float* __restrict__ b4,
        float* __restrict__ out, int nrows) {
    extern __shared__ char lds[];
    const int t = threadIdx.x;
    const int wv = t >> 6;
    const int lane = t & 63;
    char* bufA = lds + wv * 16384;   // 8KB chunk buffer
    char* bufB = bufA + 8192;        // 8KB chunk buffer

    const long long wrow0 =
        ((long long)blockIdx.x * 2 + wv) * (NT * TILE_ROWS);
    const char* xbase = reinterpret_cast<const char*>(x + wrow0 * 64);

    // R6-proven per-lane staging source offset (inverse of read swizzle),
    // within one 64-row x 64B sub-chunk (row stride in x = 256B).
    const int h = lane >> 3;
    const int q = (lane & 7) ^ h;
    const int stage_off = (2 * h + (q >> 2)) * 256 + (q & 3) * 16;

    // R6-proven per-lane LDS read offsets (row r = lane within sub-chunk).
    const int R = lane >> 1;
    const int p2 = lane & 1;
    const int r7 = R & 7;
    int roff[4];
#pragma unroll
    for (int j = 0; j < 4; ++j)
        roff[j] = R * 128 + (((j + 4 * p2) ^ r7) << 4);

    // Stage global chunk gc (tile gc>>2, col-chunk gc&3) into buf.
    auto STAGE = [&](int gc, char* buf) {
        const char* s0 = xbase + (gc >> 2) * (TILE_ROWS * 256) +
                         (gc & 3) * 64 + stage_off;
#pragma unroll
        for (int k = 0; k < 4; ++k)
            __builtin_amdgcn_global_load_lds((as1p)(s0 + k * 4096),
                                             (as3p)(buf + k * 1024), 16, 0, 0);
        const char* s1 = s0 + 64 * 256;   // rows 64..127 of the tile
#pragma unroll
        for (int k = 0; k < 4; ++k)
            __builtin_amdgcn_global_load_lds((as1p)(s1 + k * 4096),
                                             (as3p)(buf + 4096 + k * 1024),
                                             16, 0, 0);
    };

    STAGE(0, bufA);   // prologue

#pragma unroll 1
    for (int tt = 0; tt < NT; ++tt) {
        float acc0[32], acc1[32];
#pragma unroll
        for (int o = 0; o < 32; ++o) {
            const float bb = b0[o];
            acc0[o] = bb;
            acc1[o] = bb;
        }

#pragma unroll 1
        for (int c = 0; c < 4; ++c) {
            const int gc = tt * 4 + c;
            char* cur = (gc & 1) ? bufB : bufA;
            char* oth = (gc & 1) ? bufA : bufB;

            if (gc + 1 < TOTAL_CHUNKS) {
                STAGE(gc + 1, oth);
                // 8 new loads in flight; drain everything older (the
                // current chunk's 8 loads, plus any earlier stores).
                asm volatile("s_waitcnt vmcnt(8)" ::: "memory");
            } else {
                asm volatile("s_waitcnt vmcnt(0)" ::: "memory");
            }
            __builtin_amdgcn_sched_barrier(0);

            // Conflict-free swizzled reads: 4x ds_read_b128 per row.
            float xr0[16], xr1[16];
#pragma unroll
            for (int j = 0; j < 4; ++j) {
                const float4 v =
                    *reinterpret_cast<const float4*>(cur + roff[j]);
                xr0[4 * j + 0] = v.x; xr0[4 * j + 1] = v.y;
                xr0[4 * j + 2] = v.z; xr0[4 * j + 3] = v.w;
            }
#pragma unroll
            for (int j = 0; j < 4; ++j) {
                const float4 v =
                    *reinterpret_cast<const float4*>(cur + 4096 + roff[j]);
                xr1[4 * j + 0] = v.x; xr1[4 * j + 1] = v.y;
                xr1[4 * j + 2] = v.z; xr1[4 * j + 3] = v.w;
            }

            // Layer-0 partial: 16 i-values x 32 outputs, 2 rows share each
            // s_loaded weight. Plain fmaf keeps weights on the scalar pipe.
            const float* Wc = W0 + (c << 9);   // 16 rows * 32 cols per chunk
#pragma unroll
            for (int idx = 0; idx < 16; ++idx) {
                const float v0 = xr0[idx];
                const float v1 = xr1[idx];
#pragma unroll
                for (int o = 0; o < 32; ++o) {
                    const float w = Wc[idx * 32 + o];
                    acc0[o] = fmaf(v0, w, acc0[o]);
                    acc1[o] = fmaf(v1, w, acc1[o]);
                }
            }
        }

        // ReLU on h0
#pragma unroll
        for (int o = 0; o < 32; ++o) {
            acc0[o] = fmaxf(acc0[o], 0.0f);
            acc1[o] = fmaxf(acc1[o], 0.0f);
        }

        // Tail layers (next tile's chunk-0 DMA flies during these).
        float h1a[12], h1b[12], h2a[8], h2b[8], h3a[6], h3b[6], h4a[2], h4b[2];
        layer2<32, 12, true>(W1, b1, acc0, acc1, h1a, h1b);
        layer2<12, 8, true>(W2, b2, h1a, h1b, h2a, h2b);
        layer2<8, 6, true>(W3, b3, h2a, h2b, h3a, h3b);
        layer2<6, 2, false>(W4, b4, h3a, h3b, h4a, h4b);

        const long long r = wrow0 + (long long)tt * TILE_ROWS + lane;
        float2* outv = reinterpret_cast<float2*>(out);
        outv[r]      = make_float2(h4a[0], h4a[1]);
        outv[r + 64] = make_float2(h4b[0], h4b[1]);
    }
}

extern "C" void kernel_launch(void* const* d_in, const int* in_sizes, int n_in,
                              void* d_out, int out_size, void* d_ws, size_t ws_size,
                              hipStream_t stream) {
    const float* x  = (const float*)d_in[0];
    const float* W0 = (const float*)d_in[1];
    const float* b0 = (const float*)d_in[2];
    const float* W1 = (const float*)d_in[3];
    const float* b1 = (const float*)d_in[4];
    const float* W2 = (const float*)d_in[5];
    const float* b2 = (const float*)d_in[6];
    const float* W3 = (const float*)d_in[7];
    const float* b3 = (const float*)d_in[8];
    const float* W4 = (const float*)d_in[9];
    const float* b4 = (const float*)d_in[10];
    float* out = (float*)d_out;

    const int nrows = in_sizes[0] / 64;                      // 1,048,576
    const int rows_per_block = 2 * NT * TILE_ROWS;           // 512
    const int grid = nrows / rows_per_block;                 // 2048 (exact)
    const size_t shmem = 2 * 16384;                          // 32 KiB/block

    mlp_kernel<<<grid, BLOCK, shmem, stream>>>(x, W0, b0, W1, b1, W2, b2,
                                               W3, b3, W4, b4, out, nrows);
}